// Round 9
// baseline (67.059 us; speedup 1.0000x reference)
//
#include <hip/hip_runtime.h>

// Chamfer via MFMA — R21: R16 revert + pragma-fused v_min3 folds.
// R20 post-mortem: inline-asm v_min3 reading MFMA results FAILED
// correctness (absmax 12544) — hipcc's MFMA/inline-asm hazard modeling is
// unreliable (cf. guide rule #18). NO inline asm near MFMA outputs.
// R21 gets the same fold fusion through the compiler: fold helper scoped
// with #pragma float_control(precise, off) -> fminf chain carries nnan
// flags -> AMDGPU backend min3 combine emits ONE v_min3_f32 per fold via
// the normal scheduler (hazards handled). Scope is the helper ONLY:
// epilogue fminf/sqrtf stay precise. min3(a,b,c)==fminf(fminf(a,b),c) on
// the all-finite d2 stream -> partials BITWISE identical, final kernel
// unchanged, absmax 0.0 preserved.
// Also kept from R20 (safe): own+opp global loads issued back-to-back at
// entry (overlaps the two cold-HBM latencies; ws-poison evicts L2/LLC).
// Theory recap (R17 probe): warm loop = 7.6 µs/rep; VALU 162k cyc/SIMD =
// ~98k unfused 2x v_min + ~60k v_accvgpr round-trips vs 49k min3 floor.
// This round halves the first term. Everything else byte-for-byte R16
// (65.5 µs): grid 256=(batch,dir) x 1024 thr, 64 KB LDS, 1-deep SSA
// A-prefetch, same epilogue order, same part[] layout.
// (Packing PROVEN R6-R12: A k {psqh,psql,-2ph|-2pl...}, B k {1,1,qh|ql...};
//  d2 = psq+qsq-2p.q in one v_mfma_f32_32x32x16_bf16 per 32x32 tile.)

typedef short bf16x8 __attribute__((ext_vector_type(8)));
typedef float f32x16 __attribute__((ext_vector_type(16)));

#define ONE_BF 0x3f80

__device__ __forceinline__ unsigned short f2bf(float x) {
    unsigned u = __float_as_uint(x);
    u += 0x7fffu + ((u >> 16) & 1u);          // round-to-nearest-even
    return (unsigned short)(u >> 16);
}
__device__ __forceinline__ float bf2f(unsigned short h) {
    return __uint_as_float(((unsigned)h) << 16);
}
// Fold helpers: fast-math scoped HERE ONLY so the minnum chain gets nnan
// flags and the backend fuses to v_min3_f32 / keeps a single v_min_f32.
// Values identical to precise fminf on finite inputs (all d2 finite).
__device__ __forceinline__ float fold2(float a, float b) {
#pragma float_control(precise, off)
    return fminf(a, b);
}
__device__ __forceinline__ float fold3(float a, float b, float c) {
#pragma float_control(precise, off)
    return fminf(fminf(a, b), c);
}

__global__ __launch_bounds__(1024, 4) void chamfer_dir(
    const float4* __restrict__ P, const float4* __restrict__ Q,
    float* __restrict__ part)
{
    __shared__ short lAh[1024 * 8];   // A k-slots 0-7  (16 KB)
    __shared__ short lAl[1024 * 8];   // A k-slots 8-15 (16 KB)
    __shared__ short lB[1024 * 16];   // B interleaved [pt][half][8] (32 KB)
    // total 64 KB -> 1 block/CU with grid 256 = CU count

    const int blk   = blockIdx.x;      // 0..255
    const int batch = blk >> 1;        // 0..127
    const int dir   = blk & 1;         // 0: rows=P cols=Q; 1: swapped
    const int t     = threadIdx.x;     // 0..1023
    const int base  = batch << 10;

    const float4* __restrict__ ownb = (dir ? Q : P) + base;   // rows
    const float4* __restrict__ oppb = (dir ? P : Q) + base;   // cols

    // Issue BOTH cold global loads back-to-back (overlap HBM latency).
    float4 vown = ownb[t];
    float4 vopp = oppb[t];

    // ---- Pack row point into LDS A-fragments ----
    {
        float4 v = vown;
        float psq = v.y * v.y + v.z * v.z + v.w * v.w;
        unsigned short psqh = f2bf(psq);
        unsigned short psql = f2bf(psq - bf2f(psqh));
        unsigned short yh = f2bf(v.y), zh = f2bf(v.z), wh = f2bf(v.w);
        unsigned short m2yh = f2bf(-2.0f * bf2f(yh));
        unsigned short m2zh = f2bf(-2.0f * bf2f(zh));
        unsigned short m2wh = f2bf(-2.0f * bf2f(wh));
        unsigned short m2yl = f2bf(-2.0f * (v.y - bf2f(yh)));
        unsigned short m2zl = f2bf(-2.0f * (v.z - bf2f(zh)));
        unsigned short m2wl = f2bf(-2.0f * (v.w - bf2f(wh)));
        bf16x8 ah = { (short)psqh, (short)psql, (short)m2yh, (short)m2zh,
                      (short)m2wh, (short)m2yl, (short)m2zl, (short)m2wl };
        bf16x8 al = { (short)m2yh, (short)m2zh, (short)m2wh,
                      (short)ONE_BF, (short)ONE_BF, 0, 0, 0 };
        *(bf16x8*)&lAh[t * 8] = ah;
        *(bf16x8*)&lAl[t * 8] = al;
    }
    // ---- Pack col point into LDS B-fragments ----
    {
        float4 v = vopp;
        float qsq = v.y * v.y + v.z * v.z + v.w * v.w;
        unsigned short qsqh = f2bf(qsq);
        unsigned short qsql = f2bf(qsq - bf2f(qsqh));
        unsigned short yh = f2bf(v.y), zh = f2bf(v.z), wh = f2bf(v.w);
        unsigned short yl = f2bf(v.y - bf2f(yh));
        unsigned short zl = f2bf(v.z - bf2f(zh));
        unsigned short wl = f2bf(v.w - bf2f(wh));
        bf16x8 bh = { (short)ONE_BF, (short)ONE_BF, (short)yh, (short)zh,
                      (short)wh, (short)yh, (short)zh, (short)wh };
        bf16x8 bl = { (short)yl, (short)zl, (short)wl,
                      (short)qsqh, (short)qsql, 0, 0, 0 };
        *(bf16x8*)&lB[t * 16]     = bh;
        *(bf16x8*)&lB[t * 16 + 8] = bl;
    }
    __syncthreads();

    const int lane = t & 63;
    const int half = lane >> 5;    // k-half: 0 -> slots 0-7, 1 -> 8-15
    const int l31  = lane & 31;
    const int wv   = t >> 6;       // 0..15

    // Byte-addressed A base; all loop offsets are compile-time immediates.
    const char* __restrict__ aB =
        (const char*)(half ? lAl : lAh) + l31 * 16;

    // Two col-tiles per wave: c0 = wv*2, c0+1
    const int c0 = wv << 1;
    bf16x8 bf0 = *(const bf16x8*)&lB[((((c0)     << 5) + l31) * 2 + half) * 8];
    bf16x8 bf1 = *(const bf16x8*)&lB[((((c0 + 1) << 5) + l31) * 2 + half) * 8];

    f32x16 zf;
#pragma unroll
    for (int j = 0; j < 16; ++j) zf[j] = 0.0f;

    f32x16 acc0, acc1;

    // Prologue: load pair 0 into set A (1-deep SSA prefetch, R16).
    bf16x8 afA0 = *(const bf16x8*)(aB);
    bf16x8 afA1 = *(const bf16x8*)(aB + 512);
    bf16x8 afB0 = afA0, afB1 = afA1;   // dead init

#pragma unroll
    for (int i = 0; i < 16; ++i) {
        bf16x8 f0, f1;
        if ((i & 1) == 0) { f0 = afA0; f1 = afA1; }
        else              { f0 = afB0; f1 = afB1; }
        // Prefetch pair i+1 into the OTHER set before this pair's MFMAs.
        if (i < 15) {
            if ((i & 1) == 0) {
                afB0 = *(const bf16x8*)(aB + ((i + 1) << 10));
                afB1 = *(const bf16x8*)(aB + ((i + 1) << 10) + 512);
            } else {
                afA0 = *(const bf16x8*)(aB + ((i + 1) << 10));
                afA1 = *(const bf16x8*)(aB + ((i + 1) << 10) + 512);
            }
        }
        f32x16 ca = __builtin_amdgcn_mfma_f32_32x32x16_bf16(f0, bf0, zf, 0, 0, 0);
        f32x16 cb = __builtin_amdgcn_mfma_f32_32x32x16_bf16(f1, bf0, zf, 0, 0, 0);
        if (i == 0) {
#pragma unroll
            for (int j = 0; j < 16; ++j) acc0[j] = fold2(ca[j], cb[j]);
        } else {
#pragma unroll
            for (int j = 0; j < 16; ++j) acc0[j] = fold3(ca[j], cb[j], acc0[j]);
        }
        f32x16 cc = __builtin_amdgcn_mfma_f32_32x32x16_bf16(f0, bf1, zf, 0, 0, 0);
        f32x16 cd = __builtin_amdgcn_mfma_f32_32x32x16_bf16(f1, bf1, zf, 0, 0, 0);
        if (i == 0) {
#pragma unroll
            for (int j = 0; j < 16; ++j) acc1[j] = fold2(cc[j], cd[j]);
        } else {
#pragma unroll
            for (int j = 0; j < 16; ++j) acc1[j] = fold3(cc[j], cd[j], acc1[j]);
        }
    }

    // Epilogue: 16->1 tree, cross-half shfl, sqrt, wave-sum, wave partial.
    // (PRECISE math, identical arithmetic + order to R16 -> bitwise-same)
    float m0 = acc0[0], m1 = acc1[0];
#pragma unroll
    for (int j = 1; j < 16; ++j) { m0 = fminf(m0, acc0[j]); m1 = fminf(m1, acc1[j]); }
    m0 = fminf(m0, __shfl_xor(m0, 32, 64));
    m1 = fminf(m1, __shfl_xor(m1, 32, 64));

    float s = 0.0f;
    if (half == 0)
        s = sqrtf(fmaxf(m0, 0.0f) + 1e-12f) + sqrtf(fmaxf(m1, 0.0f) + 1e-12f);
#pragma unroll
    for (int off = 32; off; off >>= 1) s += __shfl_down(s, off, 64);
    if (lane == 0) part[(blk << 4) + wv] = s;   // == batch*32 + dir*16 + w
}

__global__ __launch_bounds__(256) void chamfer_final(
    const float* __restrict__ part, float* __restrict__ out)
{
    __shared__ float ws[4];
    const int t = threadIdx.x;
    // Same linear 4096-partial array + same summation order as R14/R16.
    float s = 0.0f;
#pragma unroll
    for (int k = 0; k < 4; ++k) {
        const float4 w = *(const float4*)&part[(t + (k << 8)) << 2];
        float bk = ((w.x + w.y) + w.z) + w.w;
        s = (k == 0) ? bk : (s + bk);
    }
#pragma unroll
    for (int off = 32; off; off >>= 1) s += __shfl_down(s, off, 64);
    if ((t & 63) == 0) ws[t >> 6] = s;
    __syncthreads();
    if (t == 0) out[0] = ws[0] + ws[1] + ws[2] + ws[3];
}

extern "C" void kernel_launch(void* const* d_in, const int* in_sizes, int n_in,
                              void* d_out, int out_size, void* d_ws, size_t ws_size,
                              hipStream_t stream) {
    const float4* P = (const float4*)d_in[0];
    const float4* Q = (const float4*)d_in[1];
    float* out  = (float*)d_out;
    float* part = (float*)d_ws;   // 4096 per-wave partials (16 KB)

    chamfer_dir<<<dim3(128 * 2), dim3(1024), 0, stream>>>(P, Q, part);
    chamfer_final<<<dim3(1), dim3(256), 0, stream>>>(part, out);
}

// Round 10
// 66.871 us; speedup vs baseline: 1.0028x; 1.0028x over previous
//
#include <hip/hip_runtime.h>

// Chamfer via MFMA — R22: COMPACT rolled loop to kill the cold-I-cache
// intercept. R17 probe decomposition: chamfer_dir = 16 µs intercept +
// 7.6 µs/rep slope. Pack+launch explain ~5 µs of the intercept; the rest
// tracks the ~11 KB fully-unrolled body (~1300 insts) that every CU's
// frontend cold-fetches on the first pass (reps 2..12 run I-warm -> cost
// hides in the intercept, which is why FOUR loop-restructure rounds were
// all neutral). R22 rolls the main loop: 15 iterations of a ~75-inst body
// (#pragma unroll 1), i=0 peeled into the prologue. ~2.5 KB total code.
// Explicit SSA prefetch dropped (R14 vs R16: worth ~0, doubles the body).
// BITWISE SAFETY: per-element fold sequence identical to R16/R21
// (fold2 at i=0, fold3 i>=1, same operand order); pack, epilogue order,
// part[] layout, final kernel untouched -> absmax 0.0 preserved.
// Kept from R21: scoped-fast-math fold helpers (v_min3 candidate),
// paired early global loads. NO inline asm near MFMA (R20 lesson).
// (Packing PROVEN R6-R12: A k {psqh,psql,-2ph|-2pl...}, B k {1,1,qh|ql...};
//  d2 = psq+qsq-2p.q in one v_mfma_f32_32x32x16_bf16 per 32x32 tile.)

typedef short bf16x8 __attribute__((ext_vector_type(8)));
typedef float f32x16 __attribute__((ext_vector_type(16)));

#define ONE_BF 0x3f80

__device__ __forceinline__ unsigned short f2bf(float x) {
    unsigned u = __float_as_uint(x);
    u += 0x7fffu + ((u >> 16) & 1u);          // round-to-nearest-even
    return (unsigned short)(u >> 16);
}
__device__ __forceinline__ float bf2f(unsigned short h) {
    return __uint_as_float(((unsigned)h) << 16);
}
// Fold helpers: fast-math scoped HERE ONLY (min3 fusion candidate).
// Values identical to precise fminf on finite inputs (all d2 finite).
__device__ __forceinline__ float fold2(float a, float b) {
#pragma float_control(precise, off)
    return fminf(a, b);
}
__device__ __forceinline__ float fold3(float a, float b, float c) {
#pragma float_control(precise, off)
    return fminf(fminf(a, b), c);
}

__global__ __launch_bounds__(1024, 4) void chamfer_dir(
    const float4* __restrict__ P, const float4* __restrict__ Q,
    float* __restrict__ part)
{
    __shared__ short lAh[1024 * 8];   // A k-slots 0-7  (16 KB)
    __shared__ short lAl[1024 * 8];   // A k-slots 8-15 (16 KB)
    __shared__ short lB[1024 * 16];   // B interleaved [pt][half][8] (32 KB)
    // total 64 KB -> 1 block/CU with grid 256 = CU count

    const int blk   = blockIdx.x;      // 0..255
    const int batch = blk >> 1;        // 0..127
    const int dir   = blk & 1;         // 0: rows=P cols=Q; 1: swapped
    const int t     = threadIdx.x;     // 0..1023
    const int base  = batch << 10;

    const float4* __restrict__ ownb = (dir ? Q : P) + base;   // rows
    const float4* __restrict__ oppb = (dir ? P : Q) + base;   // cols

    // Issue BOTH cold global loads back-to-back (overlap HBM latency).
    float4 vown = ownb[t];
    float4 vopp = oppb[t];

    // ---- Pack row point into LDS A-fragments ----
    {
        float4 v = vown;
        float psq = v.y * v.y + v.z * v.z + v.w * v.w;
        unsigned short psqh = f2bf(psq);
        unsigned short psql = f2bf(psq - bf2f(psqh));
        unsigned short yh = f2bf(v.y), zh = f2bf(v.z), wh = f2bf(v.w);
        unsigned short m2yh = f2bf(-2.0f * bf2f(yh));
        unsigned short m2zh = f2bf(-2.0f * bf2f(zh));
        unsigned short m2wh = f2bf(-2.0f * bf2f(wh));
        unsigned short m2yl = f2bf(-2.0f * (v.y - bf2f(yh)));
        unsigned short m2zl = f2bf(-2.0f * (v.z - bf2f(zh)));
        unsigned short m2wl = f2bf(-2.0f * (v.w - bf2f(wh)));
        bf16x8 ah = { (short)psqh, (short)psql, (short)m2yh, (short)m2zh,
                      (short)m2wh, (short)m2yl, (short)m2zl, (short)m2wl };
        bf16x8 al = { (short)m2yh, (short)m2zh, (short)m2wh,
                      (short)ONE_BF, (short)ONE_BF, 0, 0, 0 };
        *(bf16x8*)&lAh[t * 8] = ah;
        *(bf16x8*)&lAl[t * 8] = al;
    }
    // ---- Pack col point into LDS B-fragments ----
    {
        float4 v = vopp;
        float qsq = v.y * v.y + v.z * v.z + v.w * v.w;
        unsigned short qsqh = f2bf(qsq);
        unsigned short qsql = f2bf(qsq - bf2f(qsqh));
        unsigned short yh = f2bf(v.y), zh = f2bf(v.z), wh = f2bf(v.w);
        unsigned short yl = f2bf(v.y - bf2f(yh));
        unsigned short zl = f2bf(v.z - bf2f(zh));
        unsigned short wl = f2bf(v.w - bf2f(wh));
        bf16x8 bh = { (short)ONE_BF, (short)ONE_BF, (short)yh, (short)zh,
                      (short)wh, (short)yh, (short)zh, (short)wh };
        bf16x8 bl = { (short)yl, (short)zl, (short)wl,
                      (short)qsqh, (short)qsql, 0, 0, 0 };
        *(bf16x8*)&lB[t * 16]     = bh;
        *(bf16x8*)&lB[t * 16 + 8] = bl;
    }
    __syncthreads();

    const int lane = t & 63;
    const int half = lane >> 5;    // k-half: 0 -> slots 0-7, 1 -> 8-15
    const int l31  = lane & 31;
    const int wv   = t >> 6;       // 0..15

    // Byte-addressed A base (lane row offset folded in).
    const char* __restrict__ aB =
        (const char*)(half ? lAl : lAh) + l31 * 16;

    // Two col-tiles per wave: c0 = wv*2, c0+1
    const int c0 = wv << 1;
    bf16x8 bf0 = *(const bf16x8*)&lB[((((c0)     << 5) + l31) * 2 + half) * 8];
    bf16x8 bf1 = *(const bf16x8*)&lB[((((c0 + 1) << 5) + l31) * 2 + half) * 8];

    f32x16 zf;
#pragma unroll
    for (int j = 0; j < 16; ++j) zf[j] = 0.0f;

    f32x16 acc0, acc1;

    // ---- Prologue: row-tile pair 0 (fold2, as in R16's i==0 peel) ----
    {
        bf16x8 f0 = *(const bf16x8*)(aB);
        bf16x8 f1 = *(const bf16x8*)(aB + 512);
        f32x16 ca = __builtin_amdgcn_mfma_f32_32x32x16_bf16(f0, bf0, zf, 0, 0, 0);
        f32x16 cb = __builtin_amdgcn_mfma_f32_32x32x16_bf16(f1, bf0, zf, 0, 0, 0);
#pragma unroll
        for (int j = 0; j < 16; ++j) acc0[j] = fold2(ca[j], cb[j]);
        f32x16 cc = __builtin_amdgcn_mfma_f32_32x32x16_bf16(f0, bf1, zf, 0, 0, 0);
        f32x16 cd = __builtin_amdgcn_mfma_f32_32x32x16_bf16(f1, bf1, zf, 0, 0, 0);
#pragma unroll
        for (int j = 0; j < 16; ++j) acc1[j] = fold2(cc[j], cd[j]);
    }

    // ---- Rolled main loop: 15 compact iterations (~75 insts of code) ----
#pragma unroll 1
    for (int i = 1; i < 16; ++i) {
        const char* p = aB + (i << 10);
        bf16x8 f0 = *(const bf16x8*)(p);
        bf16x8 f1 = *(const bf16x8*)(p + 512);
        f32x16 ca = __builtin_amdgcn_mfma_f32_32x32x16_bf16(f0, bf0, zf, 0, 0, 0);
        f32x16 cb = __builtin_amdgcn_mfma_f32_32x32x16_bf16(f1, bf0, zf, 0, 0, 0);
#pragma unroll
        for (int j = 0; j < 16; ++j) acc0[j] = fold3(ca[j], cb[j], acc0[j]);
        f32x16 cc = __builtin_amdgcn_mfma_f32_32x32x16_bf16(f0, bf1, zf, 0, 0, 0);
        f32x16 cd = __builtin_amdgcn_mfma_f32_32x32x16_bf16(f1, bf1, zf, 0, 0, 0);
#pragma unroll
        for (int j = 0; j < 16; ++j) acc1[j] = fold3(cc[j], cd[j], acc1[j]);
    }

    // Epilogue: 16->1 tree, cross-half shfl, sqrt, wave-sum, wave partial.
    // (PRECISE math, identical arithmetic + order to R16 -> bitwise-same)
    float m0 = acc0[0], m1 = acc1[0];
#pragma unroll
    for (int j = 1; j < 16; ++j) { m0 = fminf(m0, acc0[j]); m1 = fminf(m1, acc1[j]); }
    m0 = fminf(m0, __shfl_xor(m0, 32, 64));
    m1 = fminf(m1, __shfl_xor(m1, 32, 64));

    float s = 0.0f;
    if (half == 0)
        s = sqrtf(fmaxf(m0, 0.0f) + 1e-12f) + sqrtf(fmaxf(m1, 0.0f) + 1e-12f);
#pragma unroll
    for (int off = 32; off; off >>= 1) s += __shfl_down(s, off, 64);
    if (lane == 0) part[(blk << 4) + wv] = s;   // == batch*32 + dir*16 + w
}

__global__ __launch_bounds__(256) void chamfer_final(
    const float* __restrict__ part, float* __restrict__ out)
{
    __shared__ float ws[4];
    const int t = threadIdx.x;
    // Same linear 4096-partial array + same summation order as R14/R16.
    float s = 0.0f;
#pragma unroll
    for (int k = 0; k < 4; ++k) {
        const float4 w = *(const float4*)&part[(t + (k << 8)) << 2];
        float bk = ((w.x + w.y) + w.z) + w.w;
        s = (k == 0) ? bk : (s + bk);
    }
#pragma unroll
    for (int off = 32; off; off >>= 1) s += __shfl_down(s, off, 64);
    if ((t & 63) == 0) ws[t >> 6] = s;
    __syncthreads();
    if (t == 0) out[0] = ws[0] + ws[1] + ws[2] + ws[3];
}

extern "C" void kernel_launch(void* const* d_in, const int* in_sizes, int n_in,
                              void* d_out, int out_size, void* d_ws, size_t ws_size,
                              hipStream_t stream) {
    const float4* P = (const float4*)d_in[0];
    const float4* Q = (const float4*)d_in[1];
    float* out  = (float*)d_out;
    float* part = (float*)d_ws;   // 4096 per-wave partials (16 KB)

    chamfer_dir<<<dim3(128 * 2), dim3(1024), 0, stream>>>(P, Q, part);
    chamfer_final<<<dim3(1), dim3(256), 0, stream>>>(part, out);
}